// Round 10
// baseline (212.664 us; speedup 1.0000x reference)
//
#include <hip/hip_runtime.h>
#include <hip/hip_fp16.h>

#define T_TOK 200
#define EMB   128
#define S_TILE 8
#define NT    512
#define LPAD  4

// ws layout: Wt (57344 float4 = 917504 B) | embH (100000*128*2 = 25600000 B)
#define EMBH_OFF   917504UL
#define WS_NEED    (EMBH_OFF + 25600000UL)

// ---- prep: W transpose/pack + emb fp32->fp16 convert (R8-proven) ----
__global__ __launch_bounds__(256) void prep_kernel(
    const float* __restrict__ emb,
    const float* __restrict__ W1, const float* __restrict__ W2,
    const float* __restrict__ W3,
    __half* __restrict__ embH, float4* __restrict__ ws4, int do_conv)
{
    int bid = blockIdx.x;
    if (bid < 6250) {
        if (!do_conv) return;
        size_t i = ((size_t)bid * 256 + threadIdx.x) * 8;   // 6250*256*8 = 12.8M exact
        float4 a = *(const float4*)(emb + i);
        float4 b = *(const float4*)(emb + i + 4);
        __half2 hh[4];
        hh[0] = __floats2half2_rn(a.x, a.y);
        hh[1] = __floats2half2_rn(a.z, a.w);
        hh[2] = __floats2half2_rn(b.x, b.y);
        hh[3] = __floats2half2_rn(b.z, b.w);
        *(float4*)(embH + i) = *(float4*)hh;
    } else {
        int j = (bid - 6250) * 256 + threadIdx.x;           // < 57344
        if (j < 16384) {
            int fc = j >> 9, o = j & 511;
            const float* s = W1 + (size_t)o * 128 + fc * 4;
            ws4[fc * 512 + o] = make_float4(s[0], s[1], s[2], s[3]);
        } else if (j < 49152) {
            int t = j - 16384;
            int fc = t >> 8, o = t & 255;
            const float* s = W2 + (size_t)o * 512 + fc * 4;
            ws4[16384 + fc * 256 + o] = make_float4(s[0], s[1], s[2], s[3]);
        } else {
            int t = j - 49152;
            int fc = t >> 7, o = t & 127;
            const float* s = W3 + (size_t)o * 256 + fc * 4;
            ws4[49152 + fc * 128 + o] = make_float4(s[0], s[1], s[2], s[3]);
        }
    }
}

// ---- layerT at NT=512 threads: W 16B/lane coalesced, prefetch-1 ----
template <int FIN, int FOUT, int OPT, bool RELU>
__device__ __forceinline__ void layerT(const float* __restrict__ sin,
                                       float* __restrict__ sout,
                                       const float4* __restrict__ Wt,
                                       const float* __restrict__ b, int tid)
{
    constexpr int SIN_STR  = FIN + LPAD;
    constexpr int SOUT_STR = FOUT + LPAD;
    constexpr int NO     = FOUT / OPT;      // threads covering o-dim
    constexpr int GROUPS = NT / NO;
    constexpr int SPT    = S_TILE / GROUPS; // samples per thread

    const int o0 = tid % NO;
    const int s0 = (tid / NO) * SPT;

    float acc[OPT][SPT];
#pragma unroll
    for (int i = 0; i < OPT; ++i) {
        float bi = b[o0 + i * NO];
#pragma unroll
        for (int j = 0; j < SPT; ++j) acc[i][j] = bi;
    }

    float4 wc[OPT], wn[OPT];
#pragma unroll
    for (int i = 0; i < OPT; ++i) wc[i] = Wt[(size_t)0 * FOUT + o0 + i * NO];

    int f = 0;
    for (; f < FIN - 4; f += 4) {
        const int fc = (f >> 2) + 1;
#pragma unroll
        for (int i = 0; i < OPT; ++i) wn[i] = Wt[(size_t)fc * FOUT + o0 + i * NO];
#pragma unroll
        for (int j = 0; j < SPT; ++j) {
            float4 xv = *(const float4*)&sin[(s0 + j) * SIN_STR + f];
#pragma unroll
            for (int i = 0; i < OPT; ++i) {
                acc[i][j] = fmaf(xv.x, wc[i].x, acc[i][j]);
                acc[i][j] = fmaf(xv.y, wc[i].y, acc[i][j]);
                acc[i][j] = fmaf(xv.z, wc[i].z, acc[i][j]);
                acc[i][j] = fmaf(xv.w, wc[i].w, acc[i][j]);
            }
        }
#pragma unroll
        for (int i = 0; i < OPT; ++i) wc[i] = wn[i];
    }
#pragma unroll
    for (int j = 0; j < SPT; ++j) {
        float4 xv = *(const float4*)&sin[(s0 + j) * SIN_STR + f];
#pragma unroll
        for (int i = 0; i < OPT; ++i) {
            acc[i][j] = fmaf(xv.x, wc[i].x, acc[i][j]);
            acc[i][j] = fmaf(xv.y, wc[i].y, acc[i][j]);
            acc[i][j] = fmaf(xv.z, wc[i].z, acc[i][j]);
            acc[i][j] = fmaf(xv.w, wc[i].w, acc[i][j]);
        }
    }

#pragma unroll
    for (int j = 0; j < SPT; ++j) {
#pragma unroll
        for (int i = 0; i < OPT; ++i) {
            float v = acc[i][j];
            if (RELU) v = fmaxf(v, 0.f);
            sout[(s0 + j) * SOUT_STR + o0 + i * NO] = v;
        }
    }
}

// ---- Fused pool + MLP: 512 threads = 8 waves, one wave per sample.
// 2 blocks/CU -> 16 waves/CU in BOTH phases (2x R9's concurrency). ----
template <bool USE_FP16>
__global__ __launch_bounds__(NT, 4) void fused_kernel(
    const int* __restrict__ x, const int* __restrict__ lengths,
    const float* __restrict__ emb, const __half* __restrict__ embH,
    const float4* __restrict__ Wt,
    const float* __restrict__ b1, const float* __restrict__ b2,
    const float* __restrict__ b3,
    const float* __restrict__ W4, const float* __restrict__ b4,
    float* __restrict__ out)
{
    __shared__ float bufA[S_TILE * (256 + LPAD)];   // X (str 132), H2 (str 260)
    __shared__ float bufB[S_TILE * (512 + LPAD)];   // H1 (str 516), H3 (str 132)

    const int tid  = threadIdx.x;
    const int wid  = tid >> 6;           // 0..7 -> one sample per wave
    const int lane = tid & 63;
    const int base = blockIdx.x * S_TILE;

    // ---- pool phase ----
    {
        const int s   = wid;
        const int n   = base + s;
        const int len = lengths[n];
        const int* xr = x + (size_t)n * T_TOK;

        int r0 = xr[lane];
        int r1 = xr[64 + lane];
        int r2 = xr[128 + lane];
        int r3 = xr[(192 + lane < T_TOK) ? (192 + lane) : (T_TOK - 1)];

        if (USE_FP16) {
            const int part = lane >> 4;          // token-of-quad
            const int sub  = lane & 15;          // cols [8*sub, 8*sub+8)
            float acc[8];
#pragma unroll
            for (int j = 0; j < 8; ++j) acc[j] = 0.f;

            for (int c = 0; c < 4; ++c) {
                const int coff = c * 64;
                if (coff >= len) break;
                int m = len - coff;
                if (m > 64) m = 64;
                int r = r0;
                if (c == 1) r = r1;
                if (c == 2) r = r2;
                if (c == 3) r = r3;

                for (int k = 0; k < m; k += 32) {   // 32 tokens = 8 quad-loads
                    float4 v[8];
                    int tk[8];
#pragma unroll
                    for (int i = 0; i < 8; ++i) {
                        int t  = k + 4 * i + part;          // <= 63
                        tk[i]  = t;
                        int tc = (t < m) ? t : (m - 1);     // clamp: dup line
                        int idx = __shfl(r, tc);
                        v[i] = *(const float4*)(embH + (size_t)idx * EMB + sub * 8);
                    }
#pragma unroll
                    for (int i = 0; i < 8; ++i) {
                        if (tk[i] < m) {
                            const __half2* h = (const __half2*)&v[i];
#pragma unroll
                            for (int q = 0; q < 4; ++q) {
                                float2 f = __half22float2(h[q]);
                                acc[2 * q]     += f.x;
                                acc[2 * q + 1] += f.y;
                            }
                        }
                    }
                }
            }
#pragma unroll
            for (int j = 0; j < 8; ++j) {
                acc[j] += __shfl(acc[j], lane ^ 16);
                acc[j] += __shfl(acc[j], lane ^ 32);
            }
            if (part == 0) {
                const float inv = 1.0f / (float)len;
                float* dst = &bufA[s * (EMB + LPAD) + sub * 8];
                *(float4*)(dst)     = make_float4(acc[0] * inv, acc[1] * inv,
                                                  acc[2] * inv, acc[3] * inv);
                *(float4*)(dst + 4) = make_float4(acc[4] * inv, acc[5] * inv,
                                                  acc[6] * inv, acc[7] * inv);
            }
        } else {
            const int half = lane >> 5;
            const int col4 = (lane & 31) * 4;
            float4 acc = make_float4(0.f, 0.f, 0.f, 0.f);
            for (int c = 0; c < 4; ++c) {
                const int coff = c * 64;
                if (coff >= len) break;
                int m = len - coff;
                if (m > 64) m = 64;
                int r = r0;
                if (c == 1) r = r1;
                if (c == 2) r = r2;
                if (c == 3) r = r3;
                for (int k = 0; k < m; k += 16) {
                    float4 v[8];
#pragma unroll
                    for (int i = 0; i < 8; ++i) {
                        int t  = k + 2 * i + half;
                        int tc = (t < m) ? t : (m - 1);
                        int idx = __shfl(r, tc);
                        v[i] = *(const float4*)(emb + (size_t)idx * EMB + col4);
                    }
#pragma unroll
                    for (int i = 0; i < 8; ++i) {
                        if (k + 2 * i + half < m) {
                            acc.x += v[i].x; acc.y += v[i].y;
                            acc.z += v[i].z; acc.w += v[i].w;
                        }
                    }
                }
            }
            acc.x += __shfl(acc.x, lane ^ 32);
            acc.y += __shfl(acc.y, lane ^ 32);
            acc.z += __shfl(acc.z, lane ^ 32);
            acc.w += __shfl(acc.w, lane ^ 32);
            if (half == 0) {
                const float inv = 1.0f / (float)len;
                *(float4*)&bufA[s * (EMB + LPAD) + col4] =
                    make_float4(acc.x * inv, acc.y * inv, acc.z * inv, acc.w * inv);
            }
        }
    }
    __syncthreads();

    // ---- MLP phase at 512 threads ----
    layerT<128, 512, 4, true>(bufA, bufB, Wt,         b1, tid);
    __syncthreads();
    layerT<512, 256, 4, true>(bufB, bufA, Wt + 16384, b2, tid);
    __syncthreads();
    layerT<256, 128, 2, true>(bufA, bufB, Wt + 49152, b3, tid);
    __syncthreads();

    if (tid < 2 * S_TILE) {
        int s = tid >> 1;
        int o = tid & 1;
        float accv = b4[o];
        const float* xr2 = &bufB[s * (EMB + LPAD)];
        const float* wr2 = &W4[(size_t)o * EMB];
#pragma unroll 8
        for (int f = 0; f < EMB; ++f) accv = fmaf(xr2[f], wr2[f], accv);
        out[(size_t)(base + s) * 2 + o] = accv;
    }
}

extern "C" void kernel_launch(void* const* d_in, const int* in_sizes, int n_in,
                              void* d_out, int out_size, void* d_ws, size_t ws_size,
                              hipStream_t stream)
{
    const int*   x       = (const int*)d_in[0];
    const int*   lengths = (const int*)d_in[1];
    const float* emb     = (const float*)d_in[2];
    const float* W1      = (const float*)d_in[3];
    const float* b1      = (const float*)d_in[4];
    const float* W2      = (const float*)d_in[5];
    const float* b2      = (const float*)d_in[6];
    const float* W3      = (const float*)d_in[7];
    const float* b3      = (const float*)d_in[8];
    const float* W4      = (const float*)d_in[9];
    const float* b4      = (const float*)d_in[10];
    float*       out     = (float*)d_out;

    float4* Wt   = (float4*)d_ws;
    __half* embH = (__half*)((char*)d_ws + EMBH_OFF);

    const int N = in_sizes[1];   // 4096
    const bool fp16 = (ws_size >= WS_NEED);

    if (fp16) {
        prep_kernel<<<6474, 256, 0, stream>>>(emb, W1, W2, W3, embH, Wt, 1);
        fused_kernel<true><<<N / S_TILE, NT, 0, stream>>>(
            x, lengths, emb, embH, Wt, b1, b2, b3, W4, b4, out);
    } else {
        prep_kernel<<<6474, 256, 0, stream>>>(emb, W1, W2, W3, embH, Wt, 0);
        fused_kernel<false><<<N / S_TILE, NT, 0, stream>>>(
            x, lengths, emb, embH, Wt, b1, b2, b3, W4, b4, out);
    }
}

// Round 11
// 180.628 us; speedup vs baseline: 1.1774x; 1.1774x over previous
//
#include <hip/hip_runtime.h>
#include <hip/hip_fp16.h>

#define T_TOK 200
#define EMB   128
#define LPAD  4

// ws layout: Wt (57344 float4 = 917504 B) | embH (25600000 B) | pooled (2 MB)
#define EMBH_OFF   917504UL
#define POOL_OFF   (EMBH_OFF + 25600000UL)
#define WS_NEED    (POOL_OFF + 4096UL * 128UL * 4UL)

// ---- prep: W transpose/pack + emb fp32->fp16 convert (R8-proven) ----
__global__ __launch_bounds__(256) void prep_kernel(
    const float* __restrict__ emb,
    const float* __restrict__ W1, const float* __restrict__ W2,
    const float* __restrict__ W3,
    __half* __restrict__ embH, float4* __restrict__ ws4)
{
    int bid = blockIdx.x;
    if (bid < 6250) {
        size_t i = ((size_t)bid * 256 + threadIdx.x) * 8;   // 6250*256*8 = 12.8M exact
        float4 a = *(const float4*)(emb + i);
        float4 b = *(const float4*)(emb + i + 4);
        __half2 hh[4];
        hh[0] = __floats2half2_rn(a.x, a.y);
        hh[1] = __floats2half2_rn(a.z, a.w);
        hh[2] = __floats2half2_rn(b.x, b.y);
        hh[3] = __floats2half2_rn(b.z, b.w);
        *(float4*)(embH + i) = *(float4*)hh;
    } else {
        int j = (bid - 6250) * 256 + threadIdx.x;           // < 57344
        if (j < 16384) {
            int fc = j >> 9, o = j & 511;
            const float* s = W1 + (size_t)o * 128 + fc * 4;
            ws4[fc * 512 + o] = make_float4(s[0], s[1], s[2], s[3]);
        } else if (j < 49152) {
            int t = j - 16384;
            int fc = t >> 8, o = t & 255;
            const float* s = W2 + (size_t)o * 512 + fc * 4;
            ws4[16384 + fc * 256 + o] = make_float4(s[0], s[1], s[2], s[3]);
        } else {
            int t = j - 49152;
            int fc = t >> 7, o = t & 127;
            const float* s = W3 + (size_t)o * 256 + fc * 4;
            ws4[49152 + fc * 128 + o] = make_float4(s[0], s[1], s[2], s[3]);
        }
    }
}

// ---- pool: fp16 gather, 1 sample/wave, grid N/4 -> 16 waves/CU, no LDS ----
__global__ __launch_bounds__(256) void pool_kernel(
    const int* __restrict__ x, const int* __restrict__ lengths,
    const __half* __restrict__ embH, float* __restrict__ pooled)
{
    const int tid  = threadIdx.x;
    const int wid  = tid >> 6;
    const int lane = tid & 63;
    const int n    = blockIdx.x * 4 + wid;

    const int len = lengths[n];
    const int* xr = x + (size_t)n * T_TOK;

    int r0 = xr[lane];
    int r1 = xr[64 + lane];
    int r2 = xr[128 + lane];
    int r3 = xr[(192 + lane < T_TOK) ? (192 + lane) : (T_TOK - 1)];

    const int part = lane >> 4;          // token-of-quad
    const int sub  = lane & 15;          // cols [8*sub, 8*sub+8)
    float acc[8];
#pragma unroll
    for (int j = 0; j < 8; ++j) acc[j] = 0.f;

    for (int c = 0; c < 4; ++c) {
        const int coff = c * 64;
        if (coff >= len) break;
        int m = len - coff;
        if (m > 64) m = 64;
        int r = r0;
        if (c == 1) r = r1;
        if (c == 2) r = r2;
        if (c == 3) r = r3;

        for (int k = 0; k < m; k += 32) {   // 32 tokens = 8 quad-loads in flight
            float4 v[8];
            int tk[8];
#pragma unroll
            for (int i = 0; i < 8; ++i) {
                int t  = k + 4 * i + part;          // <= 63
                tk[i]  = t;
                int tc = (t < m) ? t : (m - 1);     // clamp: dup line, ~free
                int idx = __shfl(r, tc);
                v[i] = *(const float4*)(embH + (size_t)idx * EMB + sub * 8);
            }
#pragma unroll
            for (int i = 0; i < 8; ++i) {
                if (tk[i] < m) {
                    const __half2* h = (const __half2*)&v[i];
#pragma unroll
                    for (int q = 0; q < 4; ++q) {
                        float2 f = __half22float2(h[q]);
                        acc[2 * q]     += f.x;
                        acc[2 * q + 1] += f.y;
                    }
                }
            }
        }
    }
#pragma unroll
    for (int j = 0; j < 8; ++j) {
        acc[j] += __shfl(acc[j], lane ^ 16);
        acc[j] += __shfl(acc[j], lane ^ 32);
    }
    if (part == 0) {
        const float inv = 1.0f / (float)len;
        float* dst = pooled + (size_t)n * EMB + sub * 8;
        *(float4*)(dst)     = make_float4(acc[0] * inv, acc[1] * inv,
                                          acc[2] * inv, acc[3] * inv);
        *(float4*)(dst + 4) = make_float4(acc[4] * inv, acc[5] * inv,
                                          acc[6] * inv, acc[7] * inv);
    }
}

// ---- layerT: NT=256, S_TILE-templated; W 16B/lane coalesced, prefetch-1 ----
template <int STILE, int FIN, int FOUT, int OPT, bool RELU>
__device__ __forceinline__ void layerT(const float* __restrict__ sin,
                                       float* __restrict__ sout,
                                       const float4* __restrict__ Wt,
                                       const float* __restrict__ b, int tid)
{
    constexpr int SIN_STR  = FIN + LPAD;
    constexpr int SOUT_STR = FOUT + LPAD;
    constexpr int NO     = FOUT / OPT;
    constexpr int GROUPS = 256 / NO;
    constexpr int SPT    = STILE / GROUPS;

    const int o0 = tid % NO;
    const int s0 = (tid / NO) * SPT;

    float acc[OPT][SPT];
#pragma unroll
    for (int i = 0; i < OPT; ++i) {
        float bi = b[o0 + i * NO];
#pragma unroll
        for (int j = 0; j < SPT; ++j) acc[i][j] = bi;
    }

    float4 wc[OPT], wn[OPT];
#pragma unroll
    for (int i = 0; i < OPT; ++i) wc[i] = Wt[(size_t)0 * FOUT + o0 + i * NO];

    int f = 0;
    for (; f < FIN - 4; f += 4) {
        const int fc = (f >> 2) + 1;
#pragma unroll
        for (int i = 0; i < OPT; ++i) wn[i] = Wt[(size_t)fc * FOUT + o0 + i * NO];
#pragma unroll
        for (int j = 0; j < SPT; ++j) {
            float4 xv = *(const float4*)&sin[(s0 + j) * SIN_STR + f];
#pragma unroll
            for (int i = 0; i < OPT; ++i) {
                acc[i][j] = fmaf(xv.x, wc[i].x, acc[i][j]);
                acc[i][j] = fmaf(xv.y, wc[i].y, acc[i][j]);
                acc[i][j] = fmaf(xv.z, wc[i].z, acc[i][j]);
                acc[i][j] = fmaf(xv.w, wc[i].w, acc[i][j]);
            }
        }
#pragma unroll
        for (int i = 0; i < OPT; ++i) wc[i] = wn[i];
    }
#pragma unroll
    for (int j = 0; j < SPT; ++j) {
        float4 xv = *(const float4*)&sin[(s0 + j) * SIN_STR + f];
#pragma unroll
        for (int i = 0; i < OPT; ++i) {
            acc[i][j] = fmaf(xv.x, wc[i].x, acc[i][j]);
            acc[i][j] = fmaf(xv.y, wc[i].y, acc[i][j]);
            acc[i][j] = fmaf(xv.z, wc[i].z, acc[i][j]);
            acc[i][j] = fmaf(xv.w, wc[i].w, acc[i][j]);
        }
    }

#pragma unroll
    for (int j = 0; j < SPT; ++j) {
#pragma unroll
        for (int i = 0; i < OPT; ++i) {
            float v = acc[i][j];
            if (RELU) v = fmaxf(v, 0.f);
            sout[(s0 + j) * SOUT_STR + o0 + i * NO] = v;
        }
    }
}

// ---- MLP: NT=256, S_TILE=16 (halves per-sample W traffic vs R9), grid 256 ----
#define MST 16
__global__ __launch_bounds__(256) void mlp_kernel(
    const float* __restrict__ pooled,
    const float4* __restrict__ Wt,
    const float* __restrict__ b1, const float* __restrict__ b2,
    const float* __restrict__ b3,
    const float* __restrict__ W4, const float* __restrict__ b4,
    float* __restrict__ out)
{
    __shared__ float bufA[MST * (256 + LPAD)];   // X (str 132), H2 (str 260)
    __shared__ float bufB[MST * (512 + LPAD)];   // H1 (str 516), H3 (str 132)

    const int tid  = threadIdx.x;
    const int base = blockIdx.x * MST;

    // load pooled tile: MST*32 float4, 2 per thread
    for (int idx = tid; idx < MST * 32; idx += 256) {
        int s = idx >> 5, c = idx & 31;
        *(float4*)&bufA[s * (EMB + LPAD) + c * 4] =
            *(const float4*)&pooled[(size_t)(base + s) * EMB + c * 4];
    }
    __syncthreads();

    layerT<MST, 128, 512, 4, true>(bufA, bufB, Wt,         b1, tid);
    __syncthreads();
    layerT<MST, 512, 256, 4, true>(bufB, bufA, Wt + 16384, b2, tid);
    __syncthreads();
    layerT<MST, 256, 128, 2, true>(bufA, bufB, Wt + 49152, b3, tid);
    __syncthreads();

    if (tid < 2 * MST) {
        int s = tid >> 1;
        int o = tid & 1;
        float accv = b4[o];
        const float* xr2 = &bufB[s * (EMB + LPAD)];
        const float* wr2 = &W4[(size_t)o * EMB];
#pragma unroll 8
        for (int f = 0; f < EMB; ++f) accv = fmaf(xr2[f], wr2[f], accv);
        out[(size_t)(base + s) * 2 + o] = accv;
    }
}

// =============== fallback (no ws): R3-style fused fp32, proven ===============
#define S_TILE 8
template <int FIN, int FOUT, bool RELU>
__device__ __forceinline__ void layerF(const float* __restrict__ sin,
                                       float* __restrict__ sout,
                                       const float* __restrict__ W,
                                       const float* __restrict__ b, int tid)
{
    constexpr int SIN_STR  = FIN + LPAD;
    constexpr int SOUT_STR = FOUT + LPAD;
    constexpr int OPT    = (FOUT > 256) ? (FOUT / 256) : 1;
    constexpr int NO     = FOUT / OPT;
    constexpr int GROUPS = 256 / NO;
    constexpr int SPT    = S_TILE / GROUPS;
    const int o0 = (tid % NO) * OPT;
    const int s0 = (tid / NO) * SPT;
    float acc[OPT][SPT];
#pragma unroll
    for (int i = 0; i < OPT; ++i) {
        float bi = b[o0 + i];
#pragma unroll
        for (int j = 0; j < SPT; ++j) acc[i][j] = bi;
    }
    const float* wr[OPT];
#pragma unroll
    for (int i = 0; i < OPT; ++i) wr[i] = W + (size_t)(o0 + i) * FIN;
    for (int f = 0; f < FIN; f += 4) {
        float4 w[OPT];
#pragma unroll
        for (int i = 0; i < OPT; ++i) w[i] = *(const float4*)(wr[i] + f);
#pragma unroll
        for (int j = 0; j < SPT; ++j) {
            float4 xv = *(const float4*)&sin[(s0 + j) * SIN_STR + f];
#pragma unroll
            for (int i = 0; i < OPT; ++i) {
                acc[i][j] = fmaf(xv.x, w[i].x, acc[i][j]);
                acc[i][j] = fmaf(xv.y, w[i].y, acc[i][j]);
                acc[i][j] = fmaf(xv.z, w[i].z, acc[i][j]);
                acc[i][j] = fmaf(xv.w, w[i].w, acc[i][j]);
            }
        }
    }
#pragma unroll
    for (int j = 0; j < SPT; ++j) {
#pragma unroll
        for (int i = 0; i < OPT; ++i) {
            float v = acc[i][j];
            if (RELU) v = fmaxf(v, 0.f);
            sout[(s0 + j) * SOUT_STR + (o0 + i)] = v;
        }
    }
}

__global__ __launch_bounds__(256) void fused_fallback(
    const int* __restrict__ x, const int* __restrict__ lengths,
    const float* __restrict__ emb,
    const float* __restrict__ W1, const float* __restrict__ b1,
    const float* __restrict__ W2, const float* __restrict__ b2,
    const float* __restrict__ W3, const float* __restrict__ b3,
    const float* __restrict__ W4, const float* __restrict__ b4,
    float* __restrict__ out)
{
    __shared__ float bufA[S_TILE * (256 + LPAD)];
    __shared__ float bufB[S_TILE * (512 + LPAD)];
    const int tid  = threadIdx.x;
    const int wid  = tid >> 6;
    const int lane = tid & 63;
    const int base = blockIdx.x * S_TILE;
    const int half = lane >> 5;
    const int col4 = (lane & 31) * 4;

    for (int sl = 0; sl < 2; ++sl) {
        const int s   = wid * 2 + sl;
        const int n   = base + s;
        const int len = lengths[n];
        const int* xr = x + (size_t)n * T_TOK;
        int r0 = xr[lane];
        int r1 = xr[64 + lane];
        int r2 = xr[128 + lane];
        int r3 = xr[(192 + lane < T_TOK) ? (192 + lane) : (T_TOK - 1)];
        float4 acc = make_float4(0.f, 0.f, 0.f, 0.f);
        for (int c = 0; c < 4; ++c) {
            const int coff = c * 64;
            if (coff >= len) break;
            int m = len - coff;
            if (m > 64) m = 64;
            int r = r0;
            if (c == 1) r = r1;
            if (c == 2) r = r2;
            if (c == 3) r = r3;
            for (int k = 0; k < m; k += 16) {
                float4 v[8];
#pragma unroll
                for (int i = 0; i < 8; ++i) {
                    int t  = k + 2 * i + half;
                    int tc = (t < m) ? t : (m - 1);
                    int idx = __shfl(r, tc);
                    v[i] = *(const float4*)(emb + (size_t)idx * EMB + col4);
                }
#pragma unroll
                for (int i = 0; i < 8; ++i) {
                    if (k + 2 * i + half < m) {
                        acc.x += v[i].x; acc.y += v[i].y;
                        acc.z += v[i].z; acc.w += v[i].w;
                    }
                }
            }
        }
        acc.x += __shfl(acc.x, lane ^ 32);
        acc.y += __shfl(acc.y, lane ^ 32);
        acc.z += __shfl(acc.z, lane ^ 32);
        acc.w += __shfl(acc.w, lane ^ 32);
        if (half == 0) {
            const float inv = 1.0f / (float)len;
            *(float4*)&bufA[s * (EMB + LPAD) + col4] =
                make_float4(acc.x * inv, acc.y * inv, acc.z * inv, acc.w * inv);
        }
    }
    __syncthreads();
    layerF<128, 512, true>(bufA, bufB, W1, b1, tid);
    __syncthreads();
    layerF<512, 256, true>(bufB, bufA, W2, b2, tid);
    __syncthreads();
    layerF<256, 128, true>(bufA, bufB, W3, b3, tid);
    __syncthreads();
    if (tid < 2 * S_TILE) {
        int s = tid >> 1;
        int o = tid & 1;
        float accv = b4[o];
        const float* xr2 = &bufB[s * (EMB + LPAD)];
        const float* wr2 = &W4[(size_t)o * EMB];
#pragma unroll 8
        for (int f = 0; f < EMB; ++f) accv = fmaf(xr2[f], wr2[f], accv);
        out[(size_t)(base + s) * 2 + o] = accv;
    }
}

extern "C" void kernel_launch(void* const* d_in, const int* in_sizes, int n_in,
                              void* d_out, int out_size, void* d_ws, size_t ws_size,
                              hipStream_t stream)
{
    const int*   x       = (const int*)d_in[0];
    const int*   lengths = (const int*)d_in[1];
    const float* emb     = (const float*)d_in[2];
    const float* W1      = (const float*)d_in[3];
    const float* b1      = (const float*)d_in[4];
    const float* W2      = (const float*)d_in[5];
    const float* b2      = (const float*)d_in[6];
    const float* W3      = (const float*)d_in[7];
    const float* b3      = (const float*)d_in[8];
    const float* W4      = (const float*)d_in[9];
    const float* b4      = (const float*)d_in[10];
    float*       out     = (float*)d_out;

    const int N = in_sizes[1];   // 4096

    if (ws_size < WS_NEED) {
        fused_fallback<<<N / S_TILE, 256, 0, stream>>>(x, lengths, emb,
            W1, b1, W2, b2, W3, b3, W4, b4, out);
        return;
    }

    float4* Wt     = (float4*)d_ws;
    __half* embH   = (__half*)((char*)d_ws + EMBH_OFF);
    float*  pooled = (float*)((char*)d_ws + POOL_OFF);

    prep_kernel<<<6474, 256, 0, stream>>>(emb, W1, W2, W3, embH, Wt);
    pool_kernel<<<N / 4, 256, 0, stream>>>(x, lengths, embH, pooled);
    mlp_kernel<<<N / MST, 256, 0, stream>>>(pooled, Wt, b1, b2, b3, W4, b4, out);
}

// Round 12
// 141.188 us; speedup vs baseline: 1.5062x; 1.2793x over previous
//
#include <hip/hip_runtime.h>
#include <hip/hip_fp16.h>

#define T_TOK 200
#define EMB   128
#define LPAD  4

typedef _Float16 f16x8 __attribute__((ext_vector_type(8)));
typedef float    f32x4 __attribute__((ext_vector_type(4)));

// ws layout: Wpack fp16 (458752 B) | embH (25600000 B) | pooledH (1048576 B)
// Wpack fp16 offsets: L1 0, L2 65536, L3 196608 (total 229376 fp16)
#define WP2        65536
#define WP3        196608
#define EMBH_OFF   458752UL
#define POOLH_OFF  (EMBH_OFF + 25600000UL)
#define WS_NEED    (POOLH_OFF + 1048576UL)     // ~27.1 MB (ws >= 34.8 MB proven R5)

// ---- prep: emb fp32->fp16 (blocks 0..6249) + W pack into MFMA B-frag order ----
// B-frag for 16x16x32: lane l holds B[k=(l>>4)*8+j][n=l&15], j=0..7, i.e.
// Wsrc[o=ot*16+(l&15)][k0=kc*32+(l>>4)*8 .. +7]. Entry e=(ot*KC+kc)*64+l,
// packed 8 fp16 at Wp[dstbase + e*8] -> frag load = one coalesced dwordx4/lane.
__global__ __launch_bounds__(256) void prep_kernel(
    const float* __restrict__ emb,
    const float* __restrict__ W1, const float* __restrict__ W2,
    const float* __restrict__ W3,
    __half* __restrict__ embH, __half* __restrict__ WpH)
{
    int bid = blockIdx.x;
    if (bid < 6250) {
        size_t i = ((size_t)bid * 256 + threadIdx.x) * 8;   // 12.8M floats exact
        float4 a = *(const float4*)(emb + i);
        float4 b = *(const float4*)(emb + i + 4);
        __half2 hh[4];
        hh[0] = __floats2half2_rn(a.x, a.y);
        hh[1] = __floats2half2_rn(a.z, a.w);
        hh[2] = __floats2half2_rn(b.x, b.y);
        hh[3] = __floats2half2_rn(b.z, b.w);
        *(float4*)(embH + i) = *(float4*)hh;
    } else {
        int t = (bid - 6250) * 256 + threadIdx.x;           // < 28672
        const float* Wsrc; int FIN, KC, dstbase, e;
        if (t < 8192)       { Wsrc = W1; FIN = 128; KC = 4;  dstbase = 0;    e = t; }
        else if (t < 24576) { Wsrc = W2; FIN = 512; KC = 16; dstbase = WP2;  e = t - 8192; }
        else                { Wsrc = W3; FIN = 256; KC = 8;  dstbase = WP3;  e = t - 24576; }
        int l    = e & 63, rest = e >> 6;
        int kc   = rest % KC, ot = rest / KC;
        int o    = ot * 16 + (l & 15);
        int k0   = kc * 32 + (l >> 4) * 8;
        const float* s = Wsrc + (size_t)o * FIN + k0;
        float4 a = *(const float4*)s;
        float4 b = *(const float4*)(s + 4);
        __half2 hh[4];
        hh[0] = __floats2half2_rn(a.x, a.y);
        hh[1] = __floats2half2_rn(a.z, a.w);
        hh[2] = __floats2half2_rn(b.x, b.y);
        hh[3] = __floats2half2_rn(b.z, b.w);
        *(float4*)(WpH + dstbase + (size_t)e * 8) = *(float4*)hh;
    }
}

// ---- pool: fp16 gather (R11-proven), writes pooled in fp16 ----
__global__ __launch_bounds__(256) void pool_kernel(
    const int* __restrict__ x, const int* __restrict__ lengths,
    const __half* __restrict__ embH, __half* __restrict__ poolH)
{
    const int tid  = threadIdx.x;
    const int wid  = tid >> 6;
    const int lane = tid & 63;
    const int n    = blockIdx.x * 4 + wid;

    const int len = lengths[n];
    const int* xr = x + (size_t)n * T_TOK;

    int r0 = xr[lane];
    int r1 = xr[64 + lane];
    int r2 = xr[128 + lane];
    int r3 = xr[(192 + lane < T_TOK) ? (192 + lane) : (T_TOK - 1)];

    const int part = lane >> 4;
    const int sub  = lane & 15;
    float acc[8];
#pragma unroll
    for (int j = 0; j < 8; ++j) acc[j] = 0.f;

    for (int c = 0; c < 4; ++c) {
        const int coff = c * 64;
        if (coff >= len) break;
        int m = len - coff;
        if (m > 64) m = 64;
        int r = r0;
        if (c == 1) r = r1;
        if (c == 2) r = r2;
        if (c == 3) r = r3;

        for (int k = 0; k < m; k += 32) {   // 8 quad-loads in flight
            float4 v[8];
            int tk[8];
#pragma unroll
            for (int i = 0; i < 8; ++i) {
                int t  = k + 4 * i + part;
                tk[i]  = t;
                int tc = (t < m) ? t : (m - 1);
                int idx = __shfl(r, tc);
                v[i] = *(const float4*)(embH + (size_t)idx * EMB + sub * 8);
            }
#pragma unroll
            for (int i = 0; i < 8; ++i) {
                if (tk[i] < m) {
                    const __half2* h = (const __half2*)&v[i];
#pragma unroll
                    for (int q = 0; q < 4; ++q) {
                        float2 f = __half22float2(h[q]);
                        acc[2 * q]     += f.x;
                        acc[2 * q + 1] += f.y;
                    }
                }
            }
        }
    }
#pragma unroll
    for (int j = 0; j < 8; ++j) {
        acc[j] += __shfl(acc[j], lane ^ 16);
        acc[j] += __shfl(acc[j], lane ^ 32);
    }
    if (part == 0) {
        const float inv = 1.0f / (float)len;
        __half2 p[4];
        p[0] = __floats2half2_rn(acc[0] * inv, acc[1] * inv);
        p[1] = __floats2half2_rn(acc[2] * inv, acc[3] * inv);
        p[2] = __floats2half2_rn(acc[4] * inv, acc[5] * inv);
        p[3] = __floats2half2_rn(acc[6] * inv, acc[7] * inv);
        *(float4*)(poolH + (size_t)n * EMB + sub * 8) = *(float4*)p;
    }
}

// ---- MLP via fp16 MFMA 16x16x32. Block = 256 thr = 4 waves, 16 samples.
// Wave wid owns o-slice; activations LDS fp16 row-major, stride FIN+8
// (+16B pad -> 2-way bank alias = free). fp32 acc; bias+relu at store.
// Layouts (m89-verified): A[m=lane&15][k=quad*8+j]; D col=lane&15,
// row=quad*4+reg. B packed by prep in matching frag order.
__global__ __launch_bounds__(256) void mlp_mfma(
    const __half* __restrict__ poolH, const __half* __restrict__ WpHh,
    const float* __restrict__ b1, const float* __restrict__ b2,
    const float* __restrict__ b3,
    const float* __restrict__ W4, const float* __restrict__ b4,
    float* __restrict__ out)
{
    __shared__ __align__(16) _Float16 A0[16 * 136];
    __shared__ __align__(16) _Float16 H1[16 * 520];
    __shared__ __align__(16) _Float16 H2[16 * 264];
    __shared__ __align__(16) _Float16 H3[16 * 136];

    const _Float16* Wp = (const _Float16*)WpHh;
    const int tid  = threadIdx.x;
    const int wid  = tid >> 6;
    const int lane = tid & 63;
    const int base = blockIdx.x * 16;
    const int n15  = lane & 15;
    const int quad = lane >> 4;

    // stage pooled tile: 256 threads x 16B
    {
        int s = tid >> 4, c = tid & 15;
        *(float4*)&A0[s * 136 + c * 8] =
            *(const float4*)&poolH[(size_t)(base + s) * EMB + c * 8];
    }
    __syncthreads();

    // ---- L1: 128 -> 512, wave o-slice = 128 (8 tiles), KC=4 ----
    {
        f16x8 a[4];
#pragma unroll
        for (int kc = 0; kc < 4; ++kc)
            a[kc] = *(const f16x8*)&A0[n15 * 136 + kc * 32 + quad * 8];

        f32x4 acc[8];
#pragma unroll
        for (int ot = 0; ot < 8; ++ot) acc[ot] = (f32x4){0.f, 0.f, 0.f, 0.f};

#pragma unroll
        for (int kc = 0; kc < 4; ++kc) {
#pragma unroll
            for (int ot = 0; ot < 8; ++ot) {   // 8 independent chains
                f16x8 b = *(const f16x8*)(Wp + ((size_t)(wid * 8 + ot) * 4 + kc) * 512 + lane * 8);
                acc[ot] = __builtin_amdgcn_mfma_f32_16x16x32_f16(a[kc], b, acc[ot], 0, 0, 0);
            }
        }
#pragma unroll
        for (int ot = 0; ot < 8; ++ot) {
            int o = wid * 128 + ot * 16 + n15;
            float bias = b1[o];
#pragma unroll
            for (int r = 0; r < 4; ++r) {
                float v = acc[ot][r] + bias;
                H1[(quad * 4 + r) * 520 + o] = (_Float16)fmaxf(v, 0.f);
            }
        }
    }
    __syncthreads();

    // ---- L2: 512 -> 256, wave o-slice = 64 (4 tiles), KC=16 ----
    {
        f32x4 acc[4];
#pragma unroll
        for (int ot = 0; ot < 4; ++ot) acc[ot] = (f32x4){0.f, 0.f, 0.f, 0.f};

        for (int kc = 0; kc < 16; ++kc) {
            f16x8 a = *(const f16x8*)&H1[n15 * 520 + kc * 32 + quad * 8];
#pragma unroll
            for (int ot = 0; ot < 4; ++ot) {
                f16x8 b = *(const f16x8*)(Wp + WP2 + ((size_t)(wid * 4 + ot) * 16 + kc) * 512 + lane * 8);
                acc[ot] = __builtin_amdgcn_mfma_f32_16x16x32_f16(a, b, acc[ot], 0, 0, 0);
            }
        }
#pragma unroll
        for (int ot = 0; ot < 4; ++ot) {
            int o = wid * 64 + ot * 16 + n15;
            float bias = b2[o];
#pragma unroll
            for (int r = 0; r < 4; ++r) {
                float v = acc[ot][r] + bias;
                H2[(quad * 4 + r) * 264 + o] = (_Float16)fmaxf(v, 0.f);
            }
        }
    }
    __syncthreads();

    // ---- L3: 256 -> 128, wave o-slice = 32 (2 tiles), KC=8 ----
    {
        f32x4 acc[2];
        acc[0] = (f32x4){0.f, 0.f, 0.f, 0.f};
        acc[1] = (f32x4){0.f, 0.f, 0.f, 0.f};

        for (int kc = 0; kc < 8; ++kc) {
            f16x8 a = *(const f16x8*)&H2[n15 * 264 + kc * 32 + quad * 8];
#pragma unroll
            for (int ot = 0; ot < 2; ++ot) {
                f16x8 b = *(const f16x8*)(Wp + WP3 + ((size_t)(wid * 2 + ot) * 8 + kc) * 512 + lane * 8);
                acc[ot] = __builtin_amdgcn_mfma_f32_16x16x32_f16(a, b, acc[ot], 0, 0, 0);
            }
        }
#pragma unroll
        for (int ot = 0; ot < 2; ++ot) {
            int o = wid * 32 + ot * 16 + n15;
            float bias = b3[o];
#pragma unroll
            for (int r = 0; r < 4; ++r) {
                float v = acc[ot][r] + bias;
                H3[(quad * 4 + r) * 136 + o] = (_Float16)fmaxf(v, 0.f);
            }
        }
    }
    __syncthreads();

    // ---- L4: 128 -> 2 ----
    if (tid < 32) {
        int s = tid >> 1;
        int o = tid & 1;
        float accv = b4[o];
        const _Float16* xr = &H3[s * 136];
        const float* wr = &W4[(size_t)o * EMB];
#pragma unroll 8
        for (int f = 0; f < EMB; ++f) accv = fmaf((float)xr[f], wr[f], accv);
        out[(size_t)(base + s) * 2 + o] = accv;
    }
}

// =============== fallback (no ws): R3-style fused fp32, proven ===============
#define S_TILE 8
template <int FIN, int FOUT, bool RELU>
__device__ __forceinline__ void layerF(const float* __restrict__ sin,
                                       float* __restrict__ sout,
                                       const float* __restrict__ W,
                                       const float* __restrict__ b, int tid)
{
    constexpr int SIN_STR  = FIN + LPAD;
    constexpr int SOUT_STR = FOUT + LPAD;
    constexpr int OPT    = (FOUT > 256) ? (FOUT / 256) : 1;
    constexpr int NO     = FOUT / OPT;
    constexpr int GROUPS = 256 / NO;
    constexpr int SPT    = S_TILE / GROUPS;
    const int o0 = (tid % NO) * OPT;
    const int s0 = (tid / NO) * SPT;
    float acc[OPT][SPT];
#pragma unroll
    for (int i = 0; i < OPT; ++i) {
        float bi = b[o0 + i];
#pragma unroll
        for (int j = 0; j < SPT; ++j) acc[i][j] = bi;
    }
    const float* wr[OPT];
#pragma unroll
    for (int i = 0; i < OPT; ++i) wr[i] = W + (size_t)(o0 + i) * FIN;
    for (int f = 0; f < FIN; f += 4) {
        float4 w[OPT];
#pragma unroll
        for (int i = 0; i < OPT; ++i) w[i] = *(const float4*)(wr[i] + f);
#pragma unroll
        for (int j = 0; j < SPT; ++j) {
            float4 xv = *(const float4*)&sin[(s0 + j) * SIN_STR + f];
#pragma unroll
            for (int i = 0; i < OPT; ++i) {
                acc[i][j] = fmaf(xv.x, w[i].x, acc[i][j]);
                acc[i][j] = fmaf(xv.y, w[i].y, acc[i][j]);
                acc[i][j] = fmaf(xv.z, w[i].z, acc[i][j]);
                acc[i][j] = fmaf(xv.w, w[i].w, acc[i][j]);
            }
        }
    }
#pragma unroll
    for (int j = 0; j < SPT; ++j) {
#pragma unroll
        for (int i = 0; i < OPT; ++i) {
            float v = acc[i][j];
            if (RELU) v = fmaxf(v, 0.f);
            sout[(s0 + j) * SOUT_STR + (o0 + i)] = v;
        }
    }
}

__global__ __launch_bounds__(256) void fused_fallback(
    const int* __restrict__ x, const int* __restrict__ lengths,
    const float* __restrict__ emb,
    const float* __restrict__ W1, const float* __restrict__ b1,
    const float* __restrict__ W2, const float* __restrict__ b2,
    const float* __restrict__ W3, const float* __restrict__ b3,
    const float* __restrict__ W4, const float* __restrict__ b4,
    float* __restrict__ out)
{
    __shared__ float bufA[S_TILE * (256 + LPAD)];
    __shared__ float bufB[S_TILE * (512 + LPAD)];
    const int tid  = threadIdx.x;
    const int wid  = tid >> 6;
    const int lane = tid & 63;
    const int base = blockIdx.x * S_TILE;
    const int half = lane >> 5;
    const int col4 = (lane & 31) * 4;

    for (int sl = 0; sl < 2; ++sl) {
        const int s   = wid * 2 + sl;
        const int n   = base + s;
        const int len = lengths[n];
        const int* xr = x + (size_t)n * T_TOK;
        int r0 = xr[lane];
        int r1 = xr[64 + lane];
        int r2 = xr[128 + lane];
        int r3 = xr[(192 + lane < T_TOK) ? (192 + lane) : (T_TOK - 1)];
        float4 acc = make_float4(0.f, 0.f, 0.f, 0.f);
        for (int c = 0; c < 4; ++c) {
            const int coff = c * 64;
            if (coff >= len) break;
            int m = len - coff;
            if (m > 64) m = 64;
            int r = r0;
            if (c == 1) r = r1;
            if (c == 2) r = r2;
            if (c == 3) r = r3;
            for (int k = 0; k < m; k += 16) {
                float4 v[8];
#pragma unroll
                for (int i = 0; i < 8; ++i) {
                    int t  = k + 2 * i + half;
                    int tc = (t < m) ? t : (m - 1);
                    int idx = __shfl(r, tc);
                    v[i] = *(const float4*)(emb + (size_t)idx * EMB + col4);
                }
#pragma unroll
                for (int i = 0; i < 8; ++i) {
                    if (k + 2 * i + half < m) {
                        acc.x += v[i].x; acc.y += v[i].y;
                        acc.z += v[i].z; acc.w += v[i].w;
                    }
                }
            }
        }
        acc.x += __shfl(acc.x, lane ^ 32);
        acc.y += __shfl(acc.y, lane ^ 32);
        acc.z += __shfl(acc.z, lane ^ 32);
        acc.w += __shfl(acc.w, lane ^ 32);
        if (half == 0) {
            const float inv = 1.0f / (float)len;
            *(float4*)&bufA[s * (EMB + LPAD) + col4] =
                make_float4(acc.x * inv, acc.y * inv, acc.z * inv, acc.w * inv);
        }
    }
    __syncthreads();
    layerF<128, 512, true>(bufA, bufB, W1, b1, tid);
    __syncthreads();
    layerF<512, 256, true>(bufB, bufA, W2, b2, tid);
    __syncthreads();
    layerF<256, 128, true>(bufA, bufB, W3, b3, tid);
    __syncthreads();
    if (tid < 2 * S_TILE) {
        int s = tid >> 1;
        int o = tid & 1;
        float accv = b4[o];
        const float* xr2 = &bufB[s * (EMB + LPAD)];
        const float* wr2 = &W4[(size_t)o * EMB];
#pragma unroll 8
        for (int f = 0; f < EMB; ++f) accv = fmaf(xr2[f], wr2[f], accv);
        out[(size_t)(base + s) * 2 + o] = accv;
    }
}

extern "C" void kernel_launch(void* const* d_in, const int* in_sizes, int n_in,
                              void* d_out, int out_size, void* d_ws, size_t ws_size,
                              hipStream_t stream)
{
    const int*   x       = (const int*)d_in[0];
    const int*   lengths = (const int*)d_in[1];
    const float* emb     = (const float*)d_in[2];
    const float* W1      = (const float*)d_in[3];
    const float* b1      = (const float*)d_in[4];
    const float* W2      = (const float*)d_in[5];
    const float* b2      = (const float*)d_in[6];
    const float* W3      = (const float*)d_in[7];
    const float* b3      = (const float*)d_in[8];
    const float* W4      = (const float*)d_in[9];
    const float* b4      = (const float*)d_in[10];
    float*       out     = (float*)d_out;

    const int N = in_sizes[1];   // 4096

    if (ws_size < WS_NEED) {
        fused_fallback<<<N / S_TILE, 256, 0, stream>>>(x, lengths, emb,
            W1, b1, W2, b2, W3, b3, W4, b4, out);
        return;
    }

    __half* WpH   = (__half*)d_ws;
    __half* embH  = (__half*)((char*)d_ws + EMBH_OFF);
    __half* poolH = (__half*)((char*)d_ws + POOLH_OFF);

    prep_kernel<<<6362, 256, 0, stream>>>(emb, W1, W2, W3, embH, WpH);
    pool_kernel<<<N / 4, 256, 0, stream>>>(x, lengths, embH, poolH);
    mlp_mfma<<<N / 16, 256, 0, stream>>>(poolH, WpH, b1, b2, b3, W4, b4, out);
}

// Round 13
// 130.989 us; speedup vs baseline: 1.6235x; 1.0779x over previous
//
#include <hip/hip_runtime.h>
#include <hip/hip_fp16.h>

#define T_TOK 200
#define EMB   128
#define LPAD  4

typedef _Float16 f16x8 __attribute__((ext_vector_type(8)));
typedef float    f32x4 __attribute__((ext_vector_type(4)));

// ws layout: Wpack fp16 (458752 B) | embH (25600000 B)
// Wpack fp16 offsets: L1 0, L2 65536, L3 196608 (total 229376 fp16)
#define WP2        65536
#define WP3        196608
#define EMBH_OFF   458752UL
#define WS_NEED    (EMBH_OFF + 25600000UL)

// ---- prep: emb fp32->fp16 + W pack into MFMA B-frag order (R12-proven) ----
// B-frag 16x16x32: lane l holds B[k=(l>>4)*8+j][n=l&15], j=0..7 ->
// Wsrc[o=ot*16+(l&15)][kc*32+(l>>4)*8 ..+7]; entry e=(ot*KC+kc)*64+l at
// Wp[dstbase + e*8]; frag load = one coalesced dwordx4/lane.
__global__ __launch_bounds__(256) void prep_kernel(
    const float* __restrict__ emb,
    const float* __restrict__ W1, const float* __restrict__ W2,
    const float* __restrict__ W3,
    __half* __restrict__ embH, __half* __restrict__ WpH)
{
    int bid = blockIdx.x;
    if (bid < 6250) {
        size_t i = ((size_t)bid * 256 + threadIdx.x) * 8;   // 12.8M floats exact
        float4 a = *(const float4*)(emb + i);
        float4 b = *(const float4*)(emb + i + 4);
        __half2 hh[4];
        hh[0] = __floats2half2_rn(a.x, a.y);
        hh[1] = __floats2half2_rn(a.z, a.w);
        hh[2] = __floats2half2_rn(b.x, b.y);
        hh[3] = __floats2half2_rn(b.z, b.w);
        *(float4*)(embH + i) = *(float4*)hh;
    } else {
        int t = (bid - 6250) * 256 + threadIdx.x;           // < 28672
        const float* Wsrc; int FIN, KC, dstbase, e;
        if (t < 8192)       { Wsrc = W1; FIN = 128; KC = 4;  dstbase = 0;    e = t; }
        else if (t < 24576) { Wsrc = W2; FIN = 512; KC = 16; dstbase = WP2;  e = t - 8192; }
        else                { Wsrc = W3; FIN = 256; KC = 8;  dstbase = WP3;  e = t - 24576; }
        int l    = e & 63, rest = e >> 6;
        int kc   = rest % KC, ot = rest / KC;
        int o    = ot * 16 + (l & 15);
        int k0   = kc * 32 + (l >> 4) * 8;
        const float* s = Wsrc + (size_t)o * FIN + k0;
        float4 a = *(const float4*)s;
        float4 b = *(const float4*)(s + 4);
        __half2 hh[4];
        hh[0] = __floats2half2_rn(a.x, a.y);
        hh[1] = __floats2half2_rn(a.z, a.w);
        hh[2] = __floats2half2_rn(b.x, b.y);
        hh[3] = __floats2half2_rn(b.z, b.w);
        *(float4*)(WpH + dstbase + (size_t)e * 8) = *(float4*)hh;
    }
}

// ---- fused pool + MFMA MLP: 1024 thr = 16 waves, 16 samples, grid N/16.
// Pool: wave w pools sample w (R11-proven gather), writes fp16 to LDS A0.
// MLP: o-dim split 16 ways -> per-block W traffic unchanged vs R12 but
// 4x wave concurrency. Layouts m89-verified (A[m=lane&15][k=quad*8+j];
// D col=lane&15,row=quad*4+reg). LDS strides +8 fp16 (2-way alias = free).
__global__ __launch_bounds__(1024) void fused_kernel(
    const int* __restrict__ x, const int* __restrict__ lengths,
    const __half* __restrict__ embH, const __half* __restrict__ WpHh,
    const float* __restrict__ b1, const float* __restrict__ b2,
    const float* __restrict__ b3,
    const float* __restrict__ W4, const float* __restrict__ b4,
    float* __restrict__ out)
{
    __shared__ __align__(16) _Float16 A0[16 * 136];
    __shared__ __align__(16) _Float16 H1[16 * 520];
    __shared__ __align__(16) _Float16 H2[16 * 264];
    __shared__ __align__(16) _Float16 H3[16 * 136];

    const _Float16* Wp = (const _Float16*)WpHh;
    const int tid  = threadIdx.x;
    const int wid  = tid >> 6;            // 0..15
    const int lane = tid & 63;
    const int base = blockIdx.x * 16;
    const int n15  = lane & 15;
    const int quad = lane >> 4;

    // ---- pool phase: wave wid pools sample base+wid ----
    {
        const int n   = base + wid;
        const int len = lengths[n];
        const int* xr = x + (size_t)n * T_TOK;

        int r0 = xr[lane];
        int r1 = xr[64 + lane];
        int r2 = xr[128 + lane];
        int r3 = xr[(192 + lane < T_TOK) ? (192 + lane) : (T_TOK - 1)];

        const int part = lane >> 4;
        const int sub  = lane & 15;
        float acc[8];
#pragma unroll
        for (int j = 0; j < 8; ++j) acc[j] = 0.f;

        for (int c = 0; c < 4; ++c) {
            const int coff = c * 64;
            if (coff >= len) break;
            int m = len - coff;
            if (m > 64) m = 64;
            int r = r0;
            if (c == 1) r = r1;
            if (c == 2) r = r2;
            if (c == 3) r = r3;

            for (int k = 0; k < m; k += 32) {   // 8 quad-loads in flight
                float4 v[8];
                int tk[8];
#pragma unroll
                for (int i = 0; i < 8; ++i) {
                    int t  = k + 4 * i + part;
                    tk[i]  = t;
                    int tc = (t < m) ? t : (m - 1);   // clamp: dup line, ~free
                    int idx = __shfl(r, tc);
                    v[i] = *(const float4*)(embH + (size_t)idx * EMB + sub * 8);
                }
#pragma unroll
                for (int i = 0; i < 8; ++i) {
                    if (tk[i] < m) {
                        const __half2* h = (const __half2*)&v[i];
#pragma unroll
                        for (int q = 0; q < 4; ++q) {
                            float2 f = __half22float2(h[q]);
                            acc[2 * q]     += f.x;
                            acc[2 * q + 1] += f.y;
                        }
                    }
                }
            }
        }
#pragma unroll
        for (int j = 0; j < 8; ++j) {
            acc[j] += __shfl(acc[j], lane ^ 16);
            acc[j] += __shfl(acc[j], lane ^ 32);
        }
        if (part == 0) {
            const float inv = 1.0f / (float)len;
            __half2 p[4];
            p[0] = __floats2half2_rn(acc[0] * inv, acc[1] * inv);
            p[1] = __floats2half2_rn(acc[2] * inv, acc[3] * inv);
            p[2] = __floats2half2_rn(acc[4] * inv, acc[5] * inv);
            p[3] = __floats2half2_rn(acc[6] * inv, acc[7] * inv);
            *(float4*)&A0[wid * 136 + sub * 8] = *(float4*)p;
        }
    }
    __syncthreads();

    // ---- L1: 128 -> 512, wave o-slice = 32 (2 tiles), KC=4 ----
    {
        f16x8 a[4];
#pragma unroll
        for (int kc = 0; kc < 4; ++kc)
            a[kc] = *(const f16x8*)&A0[n15 * 136 + kc * 32 + quad * 8];

        f32x4 acc[2];
        acc[0] = (f32x4){0.f, 0.f, 0.f, 0.f};
        acc[1] = (f32x4){0.f, 0.f, 0.f, 0.f};

#pragma unroll
        for (int kc = 0; kc < 4; ++kc) {
#pragma unroll
            for (int ot = 0; ot < 2; ++ot) {
                int g = wid * 2 + ot;
                f16x8 b = *(const f16x8*)(Wp + ((size_t)g * 4 + kc) * 512 + lane * 8);
                acc[ot] = __builtin_amdgcn_mfma_f32_16x16x32_f16(a[kc], b, acc[ot], 0, 0, 0);
            }
        }
#pragma unroll
        for (int ot = 0; ot < 2; ++ot) {
            int o = (wid * 2 + ot) * 16 + n15;
            float bias = b1[o];
#pragma unroll
            for (int r = 0; r < 4; ++r) {
                float v = acc[ot][r] + bias;
                H1[(quad * 4 + r) * 520 + o] = (_Float16)fmaxf(v, 0.f);
            }
        }
    }
    __syncthreads();

    // ---- L2: 512 -> 256, wave o-slice = 16 (1 tile), KC=16 ----
    {
        f32x4 acc = (f32x4){0.f, 0.f, 0.f, 0.f};
        for (int kc = 0; kc < 16; ++kc) {
            f16x8 a = *(const f16x8*)&H1[n15 * 520 + kc * 32 + quad * 8];
            f16x8 b = *(const f16x8*)(Wp + WP2 + ((size_t)wid * 16 + kc) * 512 + lane * 8);
            acc = __builtin_amdgcn_mfma_f32_16x16x32_f16(a, b, acc, 0, 0, 0);
        }
        int o = wid * 16 + n15;
        float bias = b2[o];
#pragma unroll
        for (int r = 0; r < 4; ++r) {
            float v = acc[r] + bias;
            H2[(quad * 4 + r) * 264 + o] = (_Float16)fmaxf(v, 0.f);
        }
    }
    __syncthreads();

    // ---- L3: 256 -> 128, waves 0..7 take 1 tile each, KC=8 ----
    if (wid < 8) {
        f32x4 acc = (f32x4){0.f, 0.f, 0.f, 0.f};
        for (int kc = 0; kc < 8; ++kc) {
            f16x8 a = *(const f16x8*)&H2[n15 * 264 + kc * 32 + quad * 8];
            f16x8 b = *(const f16x8*)(Wp + WP3 + ((size_t)wid * 8 + kc) * 512 + lane * 8);
            acc = __builtin_amdgcn_mfma_f32_16x16x32_f16(a, b, acc, 0, 0, 0);
        }
        int o = wid * 16 + n15;
        float bias = b3[o];
#pragma unroll
        for (int r = 0; r < 4; ++r) {
            float v = acc[r] + bias;
            H3[(quad * 4 + r) * 136 + o] = (_Float16)fmaxf(v, 0.f);
        }
    }
    __syncthreads();

    // ---- L4: 128 -> 2 ----
    if (tid < 32) {
        int s = tid >> 1;
        int o = tid & 1;
        float accv = b4[o];
        const _Float16* xr = &H3[s * 136];
        const float* wr = &W4[(size_t)o * EMB];
#pragma unroll 8
        for (int f = 0; f < EMB; ++f) accv = fmaf((float)xr[f], wr[f], accv);
        out[(size_t)(base + s) * 2 + o] = accv;
    }
}

// =============== fallback (no ws): R3-style fused fp32, proven ===============
#define S_TILE 8
template <int FIN, int FOUT, bool RELU>
__device__ __forceinline__ void layerF(const float* __restrict__ sin,
                                       float* __restrict__ sout,
                                       const float* __restrict__ W,
                                       const float* __restrict__ b, int tid)
{
    constexpr int SIN_STR  = FIN + LPAD;
    constexpr int SOUT_STR = FOUT + LPAD;
    constexpr int OPT    = (FOUT > 256) ? (FOUT / 256) : 1;
    constexpr int NO     = FOUT / OPT;
    constexpr int GROUPS = 256 / NO;
    constexpr int SPT    = S_TILE / GROUPS;
    const int o0 = (tid % NO) * OPT;
    const int s0 = (tid / NO) * SPT;
    float acc[OPT][SPT];
#pragma unroll
    for (int i = 0; i < OPT; ++i) {
        float bi = b[o0 + i];
#pragma unroll
        for (int j = 0; j < SPT; ++j) acc[i][j] = bi;
    }
    const float* wr[OPT];
#pragma unroll
    for (int i = 0; i < OPT; ++i) wr[i] = W + (size_t)(o0 + i) * FIN;
    for (int f = 0; f < FIN; f += 4) {
        float4 w[OPT];
#pragma unroll
        for (int i = 0; i < OPT; ++i) w[i] = *(const float4*)(wr[i] + f);
#pragma unroll
        for (int j = 0; j < SPT; ++j) {
            float4 xv = *(const float4*)&sin[(s0 + j) * SIN_STR + f];
#pragma unroll
            for (int i = 0; i < OPT; ++i) {
                acc[i][j] = fmaf(xv.x, w[i].x, acc[i][j]);
                acc[i][j] = fmaf(xv.y, w[i].y, acc[i][j]);
                acc[i][j] = fmaf(xv.z, w[i].z, acc[i][j]);
                acc[i][j] = fmaf(xv.w, w[i].w, acc[i][j]);
            }
        }
    }
#pragma unroll
    for (int j = 0; j < SPT; ++j) {
#pragma unroll
        for (int i = 0; i < OPT; ++i) {
            float v = acc[i][j];
            if (RELU) v = fmaxf(v, 0.f);
            sout[(s0 + j) * SOUT_STR + (o0 + i)] = v;
        }
    }
}

__global__ __launch_bounds__(256) void fused_fallback(
    const int* __restrict__ x, const int* __restrict__ lengths,
    const float* __restrict__ emb,
    const float* __restrict__ W1, const float* __restrict__ b1,
    const float* __restrict__ W2, const float* __restrict__ b2,
    const float* __restrict__ W3, const float* __restrict__ b3,
    const float* __restrict__ W4, const float* __restrict__ b4,
    float* __restrict__ out)
{
    __shared__ float bufA[S_TILE * (256 + LPAD)];
    __shared__ float bufB[S_TILE * (512 + LPAD)];
    const int tid  = threadIdx.x;
    const int wid  = tid >> 6;
    const int lane = tid & 63;
    const int base = blockIdx.x * S_TILE;
    const int half = lane >> 5;
    const int col4 = (lane & 31) * 4;

    for (int sl = 0; sl < 2; ++sl) {
        const int s   = wid * 2 + sl;
        const int n   = base + s;
        const int len = lengths[n];
        const int* xr = x + (size_t)n * T_TOK;
        int r0 = xr[lane];
        int r1 = xr[64 + lane];
        int r2 = xr[128 + lane];
        int r3 = xr[(192 + lane < T_TOK) ? (192 + lane) : (T_TOK - 1)];
        float4 acc = make_float4(0.f, 0.f, 0.f, 0.f);
        for (int c = 0; c < 4; ++c) {
            const int coff = c * 64;
            if (coff >= len) break;
            int m = len - coff;
            if (m > 64) m = 64;
            int r = r0;
            if (c == 1) r = r1;
            if (c == 2) r = r2;
            if (c == 3) r = r3;
            for (int k = 0; k < m; k += 16) {
                float4 v[8];
#pragma unroll
                for (int i = 0; i < 8; ++i) {
                    int t  = k + 2 * i + half;
                    int tc = (t < m) ? t : (m - 1);
                    int idx = __shfl(r, tc);
                    v[i] = *(const float4*)(emb + (size_t)idx * EMB + col4);
                }
#pragma unroll
                for (int i = 0; i < 8; ++i) {
                    if (k + 2 * i + half < m) {
                        acc.x += v[i].x; acc.y += v[i].y;
                        acc.z += v[i].z; acc.w += v[i].w;
                    }
                }
            }
        }
        acc.x += __shfl(acc.x, lane ^ 32);
        acc.y += __shfl(acc.y, lane ^ 32);
        acc.z += __shfl(acc.z, lane ^ 32);
        acc.w += __shfl(acc.w, lane ^ 32);
        if (half == 0) {
            const float inv = 1.0f / (float)len;
            *(float4*)&bufA[s * (EMB + LPAD) + col4] =
                make_float4(acc.x * inv, acc.y * inv, acc.z * inv, acc.w * inv);
        }
    }
    __syncthreads();
    layerF<128, 512, true>(bufA, bufB, W1, b1, tid);
    __syncthreads();
    layerF<512, 256, true>(bufB, bufA, W2, b2, tid);
    __syncthreads();
    layerF<256, 128, true>(bufA, bufB, W3, b3, tid);
    __syncthreads();
    if (tid < 2 * S_TILE) {
        int s = tid >> 1;
        int o = tid & 1;
        float accv = b4[o];
        const float* xr2 = &bufB[s * (EMB + LPAD)];
        const float* wr2 = &W4[(size_t)o * EMB];
#pragma unroll 8
        for (int f = 0; f < EMB; ++f) accv = fmaf(xr2[f], wr2[f], accv);
        out[(size_t)(base + s) * 2 + o] = accv;
    }
}

extern "C" void kernel_launch(void* const* d_in, const int* in_sizes, int n_in,
                              void* d_out, int out_size, void* d_ws, size_t ws_size,
                              hipStream_t stream)
{
    const int*   x       = (const int*)d_in[0];
    const int*   lengths = (const int*)d_in[1];
    const float* emb     = (const float*)d_in[2];
    const float* W1      = (const float*)d_in[3];
    const float* b1      = (const float*)d_in[4];
    const float* W2      = (const float*)d_in[5];
    const float* b2      = (const float*)d_in[6];
    const float* W3      = (const float*)d_in[7];
    const float* b3      = (const float*)d_in[8];
    const float* W4      = (const float*)d_in[9];
    const float* b4      = (const float*)d_in[10];
    float*       out     = (float*)d_out;

    const int N = in_sizes[1];   // 4096

    if (ws_size < WS_NEED) {
        fused_fallback<<<N / S_TILE, 256, 0, stream>>>(x, lengths, emb,
            W1, b1, W2, b2, W3, b3, W4, b4, out);
        return;
    }

    __half* WpH  = (__half*)d_ws;
    __half* embH = (__half*)((char*)d_ws + EMBH_OFF);

    prep_kernel<<<6362, 256, 0, stream>>>(emb, W1, W2, W3, embH, WpH);
    fused_kernel<<<N / 16, 1024, 0, stream>>>(x, lengths, embH, WpH,
                                              b1, b2, b3, W4, b4, out);
}

// Round 14
// 129.463 us; speedup vs baseline: 1.6427x; 1.0118x over previous
//
#include <hip/hip_runtime.h>
#include <hip/hip_fp16.h>

#define T_TOK 200
#define EMB   128
#define LPAD  4

typedef _Float16 f16x8 __attribute__((ext_vector_type(8)));
typedef float    f32x4 __attribute__((ext_vector_type(4)));

// ws layout: Wpack fp16 (458752 B) | embH (25600000 B)
// Wpack fp16 offsets: L1 0, L2 65536, L3 196608 (total 229376 fp16)
#define WP2        65536
#define WP3        196608
#define EMBH_OFF   458752UL
#define WS_NEED    (EMBH_OFF + 25600000UL)

// ---- prep: emb fp32->fp16 + W pack into MFMA B-frag order (R12-proven) ----
__global__ __launch_bounds__(256) void prep_kernel(
    const float* __restrict__ emb,
    const float* __restrict__ W1, const float* __restrict__ W2,
    const float* __restrict__ W3,
    __half* __restrict__ embH, __half* __restrict__ WpH)
{
    int bid = blockIdx.x;
    if (bid < 6250) {
        size_t i = ((size_t)bid * 256 + threadIdx.x) * 8;   // 12.8M floats exact
        float4 a = *(const float4*)(emb + i);
        float4 b = *(const float4*)(emb + i + 4);
        __half2 hh[4];
        hh[0] = __floats2half2_rn(a.x, a.y);
        hh[1] = __floats2half2_rn(a.z, a.w);
        hh[2] = __floats2half2_rn(b.x, b.y);
        hh[3] = __floats2half2_rn(b.z, b.w);
        *(float4*)(embH + i) = *(float4*)hh;
    } else {
        int t = (bid - 6250) * 256 + threadIdx.x;           // < 28672
        const float* Wsrc; int FIN, KC, dstbase, e;
        if (t < 8192)       { Wsrc = W1; FIN = 128; KC = 4;  dstbase = 0;    e = t; }
        else if (t < 24576) { Wsrc = W2; FIN = 512; KC = 16; dstbase = WP2;  e = t - 8192; }
        else                { Wsrc = W3; FIN = 256; KC = 8;  dstbase = WP3;  e = t - 24576; }
        int l    = e & 63, rest = e >> 6;
        int kc   = rest % KC, ot = rest / KC;
        int o    = ot * 16 + (l & 15);
        int k0   = kc * 32 + (l >> 4) * 8;
        const float* s = Wsrc + (size_t)o * FIN + k0;
        float4 a = *(const float4*)s;
        float4 b = *(const float4*)(s + 4);
        __half2 hh[4];
        hh[0] = __floats2half2_rn(a.x, a.y);
        hh[1] = __floats2half2_rn(a.z, a.w);
        hh[2] = __floats2half2_rn(b.x, b.y);
        hh[3] = __floats2half2_rn(b.z, b.w);
        *(float4*)(WpH + dstbase + (size_t)e * 8) = *(float4*)hh;
    }
}

// ---- fused pool + MFMA MLP: 1024 thr = 16 waves, 16 samples, grid N/16.
// R14: L1 W-frags register-prefetched BEFORE pool (latency hidden behind
// gather); L2 kc-loop batched x4; L3 frags batched x8.
__global__ __launch_bounds__(1024) void fused_kernel(
    const int* __restrict__ x, const int* __restrict__ lengths,
    const __half* __restrict__ embH, const __half* __restrict__ WpHh,
    const float* __restrict__ b1, const float* __restrict__ b2,
    const float* __restrict__ b3,
    const float* __restrict__ W4, const float* __restrict__ b4,
    float* __restrict__ out)
{
    __shared__ __align__(16) _Float16 A0[16 * 136];
    __shared__ __align__(16) _Float16 H1[16 * 520];
    __shared__ __align__(16) _Float16 H2[16 * 264];
    __shared__ __align__(16) _Float16 H3[16 * 136];

    const _Float16* Wp = (const _Float16*)WpHh;
    const int tid  = threadIdx.x;
    const int wid  = tid >> 6;            // 0..15
    const int lane = tid & 63;
    const int base = blockIdx.x * 16;
    const int n15  = lane & 15;
    const int quad = lane >> 4;

    // ---- prefetch L1 W-frags (8 x 16B/lane = 32 VGPR); latency hides
    //      behind the entire pool phase ----
    f16x8 w1f[2][4];
#pragma unroll
    for (int ot = 0; ot < 2; ++ot)
#pragma unroll
        for (int kc = 0; kc < 4; ++kc)
            w1f[ot][kc] = *(const f16x8*)(Wp + ((size_t)(wid * 2 + ot) * 4 + kc) * 512 + lane * 8);

    // ---- pool phase: wave wid pools sample base+wid (R11-proven) ----
    {
        const int n   = base + wid;
        const int len = lengths[n];
        const int* xr = x + (size_t)n * T_TOK;

        int r0 = xr[lane];
        int r1 = xr[64 + lane];
        int r2 = xr[128 + lane];
        int r3 = xr[(192 + lane < T_TOK) ? (192 + lane) : (T_TOK - 1)];

        const int part = lane >> 4;
        const int sub  = lane & 15;
        float acc[8];
#pragma unroll
        for (int j = 0; j < 8; ++j) acc[j] = 0.f;

        for (int c = 0; c < 4; ++c) {
            const int coff = c * 64;
            if (coff >= len) break;
            int m = len - coff;
            if (m > 64) m = 64;
            int r = r0;
            if (c == 1) r = r1;
            if (c == 2) r = r2;
            if (c == 3) r = r3;

            for (int k = 0; k < m; k += 32) {   // 8 quad-loads in flight
                float4 v[8];
                int tk[8];
#pragma unroll
                for (int i = 0; i < 8; ++i) {
                    int t  = k + 4 * i + part;
                    tk[i]  = t;
                    int tc = (t < m) ? t : (m - 1);   // clamp: dup line, ~free
                    int idx = __shfl(r, tc);
                    v[i] = *(const float4*)(embH + (size_t)idx * EMB + sub * 8);
                }
#pragma unroll
                for (int i = 0; i < 8; ++i) {
                    if (tk[i] < m) {
                        const __half2* h = (const __half2*)&v[i];
#pragma unroll
                        for (int q = 0; q < 4; ++q) {
                            float2 f = __half22float2(h[q]);
                            acc[2 * q]     += f.x;
                            acc[2 * q + 1] += f.y;
                        }
                    }
                }
            }
        }
#pragma unroll
        for (int j = 0; j < 8; ++j) {
            acc[j] += __shfl(acc[j], lane ^ 16);
            acc[j] += __shfl(acc[j], lane ^ 32);
        }
        if (part == 0) {
            const float inv = 1.0f / (float)len;
            __half2 p[4];
            p[0] = __floats2half2_rn(acc[0] * inv, acc[1] * inv);
            p[1] = __floats2half2_rn(acc[2] * inv, acc[3] * inv);
            p[2] = __floats2half2_rn(acc[4] * inv, acc[5] * inv);
            p[3] = __floats2half2_rn(acc[6] * inv, acc[7] * inv);
            *(float4*)&A0[wid * 136 + sub * 8] = *(float4*)p;
        }
    }
    __syncthreads();

    // ---- L1: 128 -> 512, W already in registers ----
    {
        f16x8 a[4];
#pragma unroll
        for (int kc = 0; kc < 4; ++kc)
            a[kc] = *(const f16x8*)&A0[n15 * 136 + kc * 32 + quad * 8];

        f32x4 acc[2];
        acc[0] = (f32x4){0.f, 0.f, 0.f, 0.f};
        acc[1] = (f32x4){0.f, 0.f, 0.f, 0.f};

#pragma unroll
        for (int kc = 0; kc < 4; ++kc)
#pragma unroll
            for (int ot = 0; ot < 2; ++ot)
                acc[ot] = __builtin_amdgcn_mfma_f32_16x16x32_f16(a[kc], w1f[ot][kc], acc[ot], 0, 0, 0);

#pragma unroll
        for (int ot = 0; ot < 2; ++ot) {
            int o = (wid * 2 + ot) * 16 + n15;
            float bias = b1[o];
#pragma unroll
            for (int r = 0; r < 4; ++r) {
                float v = acc[ot][r] + bias;
                H1[(quad * 4 + r) * 520 + o] = (_Float16)fmaxf(v, 0.f);
            }
        }
    }
    __syncthreads();

    // ---- L2: 512 -> 256, kc batched x4 (4 B-frag loads in flight) ----
    {
        f32x4 acc = (f32x4){0.f, 0.f, 0.f, 0.f};
#pragma unroll
        for (int kb = 0; kb < 4; ++kb) {
            f16x8 bfr[4], afr[4];
#pragma unroll
            for (int i = 0; i < 4; ++i) {
                int kc = kb * 4 + i;
                bfr[i] = *(const f16x8*)(Wp + WP2 + ((size_t)wid * 16 + kc) * 512 + lane * 8);
                afr[i] = *(const f16x8*)&H1[n15 * 520 + kc * 32 + quad * 8];
            }
#pragma unroll
            for (int i = 0; i < 4; ++i)
                acc = __builtin_amdgcn_mfma_f32_16x16x32_f16(afr[i], bfr[i], acc, 0, 0, 0);
        }
        int o = wid * 16 + n15;
        float bias = b2[o];
#pragma unroll
        for (int r = 0; r < 4; ++r) {
            float v = acc[r] + bias;
            H2[(quad * 4 + r) * 264 + o] = (_Float16)fmaxf(v, 0.f);
        }
    }
    __syncthreads();

    // ---- L3: 256 -> 128, waves 0..7, all 8 frags batched ----
    if (wid < 8) {
        f16x8 bfr[8], afr[8];
#pragma unroll
        for (int kc = 0; kc < 8; ++kc) {
            bfr[kc] = *(const f16x8*)(Wp + WP3 + ((size_t)wid * 8 + kc) * 512 + lane * 8);
            afr[kc] = *(const f16x8*)&H2[n15 * 264 + kc * 32 + quad * 8];
        }
        f32x4 acc = (f32x4){0.f, 0.f, 0.f, 0.f};
#pragma unroll
        for (int kc = 0; kc < 8; ++kc)
            acc = __builtin_amdgcn_mfma_f32_16x16x32_f16(afr[kc], bfr[kc], acc, 0, 0, 0);

        int o = wid * 16 + n15;
        float bias = b3[o];
#pragma unroll
        for (int r = 0; r < 4; ++r) {
            float v = acc[r] + bias;
            H3[(quad * 4 + r) * 136 + o] = (_Float16)fmaxf(v, 0.f);
        }
    }
    __syncthreads();

    // ---- L4: 128 -> 2 ----
    if (tid < 32) {
        int s = tid >> 1;
        int o = tid & 1;
        float accv = b4[o];
        const _Float16* xr = &H3[s * 136];
        const float* wr = &W4[(size_t)o * EMB];
#pragma unroll 8
        for (int f = 0; f < EMB; ++f) accv = fmaf((float)xr[f], wr[f], accv);
        out[(size_t)(base + s) * 2 + o] = accv;
    }
}

// =============== fallback (no ws): R3-style fused fp32, proven ===============
#define S_TILE 8
template <int FIN, int FOUT, bool RELU>
__device__ __forceinline__ void layerF(const float* __restrict__ sin,
                                       float* __restrict__ sout,
                                       const float* __restrict__ W,
                                       const float* __restrict__ b, int tid)
{
    constexpr int SIN_STR  = FIN + LPAD;
    constexpr int SOUT_STR = FOUT + LPAD;
    constexpr int OPT    = (FOUT > 256) ? (FOUT / 256) : 1;
    constexpr int NO     = FOUT / OPT;
    constexpr int GROUPS = 256 / NO;
    constexpr int SPT    = S_TILE / GROUPS;
    const int o0 = (tid % NO) * OPT;
    const int s0 = (tid / NO) * SPT;
    float acc[OPT][SPT];
#pragma unroll
    for (int i = 0; i < OPT; ++i) {
        float bi = b[o0 + i];
#pragma unroll
        for (int j = 0; j < SPT; ++j) acc[i][j] = bi;
    }
    const float* wr[OPT];
#pragma unroll
    for (int i = 0; i < OPT; ++i) wr[i] = W + (size_t)(o0 + i) * FIN;
    for (int f = 0; f < FIN; f += 4) {
        float4 w[OPT];
#pragma unroll
        for (int i = 0; i < OPT; ++i) w[i] = *(const float4*)(wr[i] + f);
#pragma unroll
        for (int j = 0; j < SPT; ++j) {
            float4 xv = *(const float4*)&sin[(s0 + j) * SIN_STR + f];
#pragma unroll
            for (int i = 0; i < OPT; ++i) {
                acc[i][j] = fmaf(xv.x, w[i].x, acc[i][j]);
                acc[i][j] = fmaf(xv.y, w[i].y, acc[i][j]);
                acc[i][j] = fmaf(xv.z, w[i].z, acc[i][j]);
                acc[i][j] = fmaf(xv.w, w[i].w, acc[i][j]);
            }
        }
    }
#pragma unroll
    for (int j = 0; j < SPT; ++j) {
#pragma unroll
        for (int i = 0; i < OPT; ++i) {
            float v = acc[i][j];
            if (RELU) v = fmaxf(v, 0.f);
            sout[(s0 + j) * SOUT_STR + (o0 + i)] = v;
        }
    }
}

__global__ __launch_bounds__(256) void fused_fallback(
    const int* __restrict__ x, const int* __restrict__ lengths,
    const float* __restrict__ emb,
    const float* __restrict__ W1, const float* __restrict__ b1,
    const float* __restrict__ W2, const float* __restrict__ b2,
    const float* __restrict__ W3, const float* __restrict__ b3,
    const float* __restrict__ W4, const float* __restrict__ b4,
    float* __restrict__ out)
{
    __shared__ float bufA[S_TILE * (256 + LPAD)];
    __shared__ float bufB[S_TILE * (512 + LPAD)];
    const int tid  = threadIdx.x;
    const int wid  = tid >> 6;
    const int lane = tid & 63;
    const int base = blockIdx.x * S_TILE;
    const int half = lane >> 5;
    const int col4 = (lane & 31) * 4;

    for (int sl = 0; sl < 2; ++sl) {
        const int s   = wid * 2 + sl;
        const int n   = base + s;
        const int len = lengths[n];
        const int* xr = x + (size_t)n * T_TOK;
        int r0 = xr[lane];
        int r1 = xr[64 + lane];
        int r2 = xr[128 + lane];
        int r3 = xr[(192 + lane < T_TOK) ? (192 + lane) : (T_TOK - 1)];
        float4 acc = make_float4(0.f, 0.f, 0.f, 0.f);
        for (int c = 0; c < 4; ++c) {
            const int coff = c * 64;
            if (coff >= len) break;
            int m = len - coff;
            if (m > 64) m = 64;
            int r = r0;
            if (c == 1) r = r1;
            if (c == 2) r = r2;
            if (c == 3) r = r3;
            for (int k = 0; k < m; k += 16) {
                float4 v[8];
#pragma unroll
                for (int i = 0; i < 8; ++i) {
                    int t  = k + 2 * i + half;
                    int tc = (t < m) ? t : (m - 1);
                    int idx = __shfl(r, tc);
                    v[i] = *(const float4*)(emb + (size_t)idx * EMB + col4);
                }
#pragma unroll
                for (int i = 0; i < 8; ++i) {
                    if (k + 2 * i + half < m) {
                        acc.x += v[i].x; acc.y += v[i].y;
                        acc.z += v[i].z; acc.w += v[i].w;
                    }
                }
            }
        }
        acc.x += __shfl(acc.x, lane ^ 32);
        acc.y += __shfl(acc.y, lane ^ 32);
        acc.z += __shfl(acc.z, lane ^ 32);
        acc.w += __shfl(acc.w, lane ^ 32);
        if (half == 0) {
            const float inv = 1.0f / (float)len;
            *(float4*)&bufA[s * (EMB + LPAD) + col4] =
                make_float4(acc.x * inv, acc.y * inv, acc.z * inv, acc.w * inv);
        }
    }
    __syncthreads();
    layerF<128, 512, true>(bufA, bufB, W1, b1, tid);
    __syncthreads();
    layerF<512, 256, true>(bufB, bufA, W2, b2, tid);
    __syncthreads();
    layerF<256, 128, true>(bufA, bufB, W3, b3, tid);
    __syncthreads();
    if (tid < 2 * S_TILE) {
        int s = tid >> 1;
        int o = tid & 1;
        float accv = b4[o];
        const float* xr2 = &bufB[s * (EMB + LPAD)];
        const float* wr2 = &W4[(size_t)o * EMB];
#pragma unroll 8
        for (int f = 0; f < EMB; ++f) accv = fmaf(xr2[f], wr2[f], accv);
        out[(size_t)(base + s) * 2 + o] = accv;
    }
}

extern "C" void kernel_launch(void* const* d_in, const int* in_sizes, int n_in,
                              void* d_out, int out_size, void* d_ws, size_t ws_size,
                              hipStream_t stream)
{
    const int*   x       = (const int*)d_in[0];
    const int*   lengths = (const int*)d_in[1];
    const float* emb     = (const float*)d_in[2];
    const float* W1      = (const float*)d_in[3];
    const float* b1      = (const float*)d_in[4];
    const float* W2      = (const float*)d_in[5];
    const float* b2      = (const float*)d_in[6];
    const float* W3      = (const float*)d_in[7];
    const float* b3      = (const float*)d_in[8];
    const float* W4      = (const float*)d_in[9];
    const float* b4      = (const float*)d_in[10];
    float*       out     = (float*)d_out;

    const int N = in_sizes[1];   // 4096

    if (ws_size < WS_NEED) {
        fused_fallback<<<N / S_TILE, 256, 0, stream>>>(x, lengths, emb,
            W1, b1, W2, b2, W3, b3, W4, b4, out);
        return;
    }

    __half* WpH  = (__half*)d_ws;
    __half* embH = (__half*)((char*)d_ws + EMBH_OFF);

    prep_kernel<<<6362, 256, 0, stream>>>(emb, W1, W2, W3, embH, WpH);
    fused_kernel<<<N / 16, 1024, 0, stream>>>(x, lengths, embH, WpH,
                                              b1, b2, b3, W4, b4, out);
}